// Round 5
// baseline (306.730 us; speedup 1.0000x reference)
//
#include <hip/hip_runtime.h>
#include <cstdint>

using u16 = unsigned short;
using u32 = unsigned int;
using u64 = unsigned long long;

typedef __attribute__((ext_vector_type(8))) short short8v;   // 8 x bf16 (raw u16)
typedef __attribute__((ext_vector_type(4))) float f32x4;

#define MFMA_BF16(a, b, c) __builtin_amdgcn_mfma_f32_16x16x32_bf16((a), (b), (c), 0, 0, 0)

__device__ __forceinline__ u16 f2bf(float f) {
  u32 u = __float_as_uint(f);
  u += 0x7fffu + ((u >> 16) & 1u);   // RNE
  return (u16)(u >> 16);
}
__device__ __forceinline__ float bf2f(u32 s) { return __uint_as_float(s << 16); }
__device__ __forceinline__ u32 cvtpk(float a, float b) {
  u32 r;
  asm("v_cvt_pk_bf16_f32 %0, %1, %2" : "=v"(r) : "v"(a), "v"(b));
  return r;
}

__device__ __forceinline__ void g2l16(const u16* g, const u16* l) {
  __builtin_amdgcn_global_load_lds(
      (const __attribute__((address_space(1))) u32*)(uintptr_t)g,
      (__attribute__((address_space(3))) u32*)(u32)(uintptr_t)l, 16, 0, 0);
}

// ---------------- fp32 -> bf16 conversion ----------------
__global__ __launch_bounds__(256) void cvt_f32_bf16(const float* __restrict__ src,
                                                    u16* __restrict__ dst, int n4) {
  int i = blockIdx.x * blockDim.x + threadIdx.x;
  if (i >= n4) return;
  const float4 v = ((const float4*)src)[i];
  const u32 w0 = cvtpk(v.x, v.y), w1 = cvtpk(v.z, v.w);
  ((u64*)dst)[i] = (u64)w0 | ((u64)w1 << 32);
}

// all four 1024x1024 weights in one launch (grid 4096 x 256)
__global__ __launch_bounds__(256) void cvt_weights(const float* __restrict__ Wq,
                                                   const float* __restrict__ Wk,
                                                   const float* __restrict__ Wv,
                                                   const float* __restrict__ Wo,
                                                   u16* __restrict__ Wqkv,
                                                   u16* __restrict__ Wob) {
  const int i = blockIdx.x * 256 + threadIdx.x;   // 0 .. 4*262144-1
  const int sel = i >> 18, j = i & 0x3ffff;
  const float* src = (sel == 0) ? Wq : (sel == 1) ? Wk : (sel == 2) ? Wv : Wo;
  u16* dst = (sel == 0) ? Wqkv : (sel == 1) ? (Wqkv + 1048576)
           : (sel == 2) ? (Wqkv + 2097152) : Wob;
  const float4 v = ((const float4*)src)[j];
  const u32 w0 = cvtpk(v.x, v.y), w1 = cvtpk(v.z, v.w);
  ((u64*)dst)[j] = (u64)w0 | ((u64)w1 << 32);
}

// ---------------- NT GEMM: C[M][N] = A[M][K] * B[N][K]^T, bf16 in, K=1024 ----
// MODE: 0 = fp32 out, 1 = bf16 out, 2 = bf16 transposed-V out ([b*1024+col][2048])
// XCD-aware bijective swizzle (grid size must be a multiple of 8).
template <int MODE>
__global__ __launch_bounds__(256) void gemm_nt(const u16* __restrict__ A,
                                               const u16* __restrict__ B,
                                               void* __restrict__ C, int ldc) {
  constexpr int K = 1024;
  __shared__ u16 As[128 * 64];
  __shared__ u16 Bs[128 * 64];
  const int tid = threadIdx.x;
  const int lane = tid & 63, wave = tid >> 6;
  const int lr = lane & 15, lg = lane >> 4;
  const int nwg = gridDim.x * gridDim.y;
  int bid = blockIdx.y * gridDim.x + blockIdx.x;
  bid = (bid & 7) * (nwg >> 3) + (bid >> 3);
  const int bm = (bid / gridDim.x) * 128, bn = (bid % gridDim.x) * 128;
  const int wm = (wave >> 1) * 64, wn = (wave & 1) * 64;
  f32x4 acc[4][4] = {};
  for (int k0 = 0; k0 < K; k0 += 64) {
#pragma unroll
    for (int it = 0; it < 4; ++it) {
      const int ci = it * 4 + wave;
      const int li = ci * 512 + lane * 8;
      const int row = li >> 6, col = li & 63;
      g2l16(A + (size_t)(bm + row) * K + k0 + col, As + ci * 512);
      g2l16(B + (size_t)(bn + row) * K + k0 + col, Bs + ci * 512);
    }
    __syncthreads();
#pragma unroll
    for (int kk = 0; kk < 2; ++kk) {
      short8v af[4], bf[4];
#pragma unroll
      for (int m = 0; m < 4; ++m)
        af[m] = *(const short8v*)&As[(wm + m * 16 + lr) * 64 + kk * 32 + lg * 8];
#pragma unroll
      for (int n = 0; n < 4; ++n)
        bf[n] = *(const short8v*)&Bs[(wn + n * 16 + lr) * 64 + kk * 32 + lg * 8];
#pragma unroll
      for (int m = 0; m < 4; ++m)
#pragma unroll
        for (int n = 0; n < 4; ++n)
          acc[m][n] = MFMA_BF16(af[m], bf[n], acc[m][n]);
    }
    __syncthreads();
  }
#pragma unroll
  for (int m = 0; m < 4; ++m)
#pragma unroll
    for (int n = 0; n < 4; ++n) {
      if (MODE == 2) {
        const int col = bn + wn + n * 16 + lr;
        const int row0 = bm + wm + m * 16 + lg * 4;
        const int bb = row0 >> 11, sl = row0 & 2047;
        const u32 w0 = cvtpk(acc[m][n][0], acc[m][n][1]);
        const u32 w1 = cvtpk(acc[m][n][2], acc[m][n][3]);
        *(u64*)((u16*)C + ((size_t)(bb * 1024 + col)) * 2048 + sl) =
            (u64)w0 | ((u64)w1 << 32);
      } else {
#pragma unroll
        for (int r = 0; r < 4; ++r) {
          const int row = bm + wm + m * 16 + lg * 4 + r;
          const int col = bn + wn + n * 16 + lr;
          if (MODE == 1)
            ((u16*)C)[(size_t)row * ldc + col] = f2bf(acc[m][n][r]);
          else
            ((float*)C)[(size_t)row * ldc + col] = acc[m][n][r];
        }
      }
    }
}

// ---------------- RoPE in-place on QK buffer [8192][2048] -------------------
// Q half additionally scaled by 0.125*log2(e)  (attn softmax runs in exp2 domain)
__global__ __launch_bounds__(256) void rope_kernel(u32* __restrict__ QKu,
                                                   const int* __restrict__ tpos) {
  const int t = blockIdx.x * 256 + threadIdx.x;   // 0 .. 8192*1024-1
  const int row = t >> 10, pp = t & 1023;
  const u32 u = QKu[t];
  const float e = bf2f(u & 0xffffu), o = bf2f(u >> 16);
  const int i = pp & 31;                          // pair index within head (dk=64)
  const float pos = (float)tpos[row & 2047];
  const float ang = pos * __expf((float)i * -0.28782313662425574f);
  float sn, cs;
  sincosf(ang, &sn, &cs);
  const float sc = (pp < 512) ? 0.18033688011112042f : 1.0f;
  cs *= sc; sn *= sc;
  const float ne = e * cs - o * sn;
  const float no = o * cs + e * sn;
  QKu[t] = cvtpk(ne, no);
}

// ---------------- causal flash attention ------------------------------------
// grid (16, 64) x 512 threads (8 waves). Block = one 128-row q-tile of one
// (b,h); gx->qt map balances work over any 4-consecutive AND stride-8 sample.
// All 1024 blocks co-resident (4/CU, 32 waves/CU). Swapped QK^T (mfma(K,Q)):
// lane owns q=lr, kv = c*16+lg*4+r; P stays in registers via cvt_pk; V B-frags
// use the matching slot->kv map. Defer-max (T13). Double-buffered K/V LDS,
// unrolled x2 (compile-time buffer index), 1 barrier per tile.
__global__ __launch_bounds__(512, 8) void attn_kernel(const u16* __restrict__ QK,
                                                      const u16* __restrict__ Vt,
                                                      u16* __restrict__ O) {
  const int gx = blockIdx.x;                       // 0..15
  const int qt = (gx < 8) ? ((gx & 1) ? gx : 15 - gx)
                          : ((gx & 1) ? 23 - gx : gx - 8);
  const int bh = blockIdx.y;
  const int h = bh & 15, b = bh >> 4;
  const int tid = threadIdx.x, lane = tid & 63, wave = tid >> 6;
  const int lr = lane & 15, lg = lane >> 4;
  __shared__ u16 Kt[2][64 * 72];
  __shared__ u16 Vs[2][64 * 72];
  const size_t bbase = (size_t)b * 2048;
  const int r_st = tid >> 3, cb_st = (tid & 7) * 8;   // staging: row, 8-u16 chunk
  const u16* Kbase = QK + (bbase + r_st) * 2048 + 1024 + h * 64 + cb_st;
  const u16* Vbase = Vt + ((size_t)(b * 16 + h) * 64 + r_st) * 2048 + cb_st;
  const int lds_off = r_st * 72 + cb_st;

  const int nkt = 2 * qt + 2;                      // always even
  const int qrow = qt * 128 + wave * 16;           // wave's first q-row
  short8v qf0, qf1;
  {
    const u16* qp = QK + (bbase + qrow + lr) * 2048 + h * 64 + lg * 8;
    qf0 = *(const short8v*)qp;
    qf1 = *(const short8v*)(qp + 32);
  }
  f32x4 oacc[4] = {};
  float m_run = -1e30f, l_run = 0.f;

  // prologue: stage tile 0 into buf0, prefetch tile 1 into regs
  short8v ka = *(const short8v*)Kbase;
  short8v va = *(const short8v*)Vbase;
  *(short8v*)&Kt[0][lds_off] = ka;
  *(short8v*)&Vs[0][lds_off] = va;
  ka = *(const short8v*)(Kbase + 64 * 2048);
  va = *(const short8v*)(Vbase + 64);

  auto compute = [&](const u16* Ktb, const u16* Vsb, const int kt) {
    if (kt * 64 > qrow + 15) return;   // wave fully masked for this tile
    f32x4 sacc[4] = {};
    __builtin_amdgcn_s_setprio(1);
#pragma unroll
    for (int c = 0; c < 4; ++c) {
      const short8v kf0 = *(const short8v*)&Ktb[(c * 16 + lr) * 72 + lg * 8];
      const short8v kf1 = *(const short8v*)&Ktb[(c * 16 + lr) * 72 + 32 + lg * 8];
      sacc[c] = MFMA_BF16(kf0, qf0, sacc[c]);
      sacc[c] = MFMA_BF16(kf1, qf1, sacc[c]);
    }
    __builtin_amdgcn_s_setprio(0);
    if (kt * 64 + 63 > qrow) {         // diagonal tile: causal mask
      const int qpos = qrow + lr;
#pragma unroll
      for (int c = 0; c < 4; ++c)
#pragma unroll
        for (int r = 0; r < 4; ++r)
          if (kt * 64 + c * 16 + lg * 4 + r > qpos) sacc[c][r] = -1e30f;
    }
    float mc[4];
#pragma unroll
    for (int c = 0; c < 4; ++c)
      mc[c] = fmaxf(fmaxf(sacc[c][0], sacc[c][1]), fmaxf(sacc[c][2], sacc[c][3]));
    float xm = fmaxf(fmaxf(mc[0], mc[1]), fmaxf(mc[2], mc[3]));
    xm = fmaxf(xm, __shfl_xor(xm, 16));
    xm = fmaxf(xm, __shfl_xor(xm, 32));
    if (!__all(xm <= m_run + 8.0f)) {  // defer-max: rescale only on real growth
      const float mn = fmaxf(m_run, xm);
      const float alpha = exp2f(m_run - mn);
      m_run = mn;
      l_run *= alpha;
#pragma unroll
      for (int r = 0; r < 4; ++r) {
        const float ao = __shfl(alpha, lg * 4 + r);
#pragma unroll
        for (int n = 0; n < 4; ++n) oacc[n][r] *= ao;
      }
    }
    float rc[4];
#pragma unroll
    for (int c = 0; c < 4; ++c) {
      f32x4 s = sacc[c];
#pragma unroll
      for (int r = 0; r < 4; ++r) s[r] = exp2f(s[r] - m_run);
      sacc[c] = s;
      rc[c] = (s[0] + s[1]) + (s[2] + s[3]);
    }
    float rs = (rc[0] + rc[1]) + (rc[2] + rc[3]);
    rs += __shfl_xor(rs, 16);
    rs += __shfl_xor(rs, 32);
    l_run += rs;
    short8v pa[2];
#pragma unroll
    for (int t = 0; t < 2; ++t) {
      union { short8v v; u32 w[4]; } P;
      P.w[0] = cvtpk(sacc[2 * t][0], sacc[2 * t][1]);
      P.w[1] = cvtpk(sacc[2 * t][2], sacc[2 * t][3]);
      P.w[2] = cvtpk(sacc[2 * t + 1][0], sacc[2 * t + 1][1]);
      P.w[3] = cvtpk(sacc[2 * t + 1][2], sacc[2 * t + 1][3]);
      pa[t] = P.v;
    }
    __builtin_amdgcn_s_setprio(1);
#pragma unroll
    for (int n = 0; n < 4; ++n) {
      const u16* vrow = &Vsb[(n * 16 + lr) * 72];
#pragma unroll
      for (int t = 0; t < 2; ++t) {
        union { short8v v; u64 d[2]; } V;
        V.d[0] = *(const u64*)(vrow + t * 32 + 4 * lg);
        V.d[1] = *(const u64*)(vrow + t * 32 + 16 + 4 * lg);
        oacc[n] = MFMA_BF16(pa[t], V.v, oacc[n]);
      }
    }
    __builtin_amdgcn_s_setprio(0);
  };

  for (int kt = 0; kt < nkt; kt += 2) {
    __syncthreads();                       // buf0 (tile kt) visible
    compute(Kt[0], Vs[0], kt);
    *(short8v*)&Kt[1][lds_off] = ka;       // stage tile kt+1
    *(short8v*)&Vs[1][lds_off] = va;
    const bool more = (kt + 2 < nkt);
    if (more) {                            // prefetch tile kt+2
      ka = *(const short8v*)(Kbase + (size_t)(kt + 2) * 64 * 2048);
      va = *(const short8v*)(Vbase + (kt + 2) * 64);
    }
    __syncthreads();                       // buf1 (tile kt+1) visible
    compute(Kt[1], Vs[1], kt + 1);
    if (more) {
      *(short8v*)&Kt[0][lds_off] = ka;     // stage tile kt+2
      *(short8v*)&Vs[0][lds_off] = va;
      ka = *(const short8v*)(Kbase + (size_t)(kt + 3) * 64 * 2048);
      va = *(const short8v*)(Vbase + (kt + 3) * 64);
    }
  }
  // ---- epilogue: O[q][d], q = qrow + lg*4 + r, d = n*16 + lr ----
#pragma unroll
  for (int r = 0; r < 4; ++r) {
    const float linv = 1.0f / __shfl(l_run, lg * 4 + r);
    const int qpos = qrow + lg * 4 + r;
#pragma unroll
    for (int n = 0; n < 4; ++n)
      O[(bbase + qpos) * 1024 + h * 64 + n * 16 + lr] = f2bf(oacc[n][r] * linv);
  }
}

// ---------------------------------------------------------------------------
extern "C" void kernel_launch(void* const* d_in, const int* in_sizes, int n_in,
                              void* d_out, int out_size, void* d_ws, size_t ws_size,
                              hipStream_t stream) {
  (void)in_sizes; (void)n_in; (void)out_size; (void)ws_size;
  const float* x   = (const float*)d_in[0];
  const int* tpos  = (const int*)d_in[1];
  const float* Wq  = (const float*)d_in[2];
  const float* Wk  = (const float*)d_in[3];
  const float* Wv  = (const float*)d_in[4];
  const float* Wo  = (const float*)d_in[5];
  float* out = (float*)d_out;

  // workspace layout (72 MB total)
  char* ws = (char*)d_ws;
  u16* xb   = (u16*)(ws);                         // 16 MB; reused as attn_out
  u16* Wqkv = (u16*)(ws + (size_t)(16 << 20));    // 6 MB  ([3072][1024])
  u16* Wob  = (u16*)(ws + (size_t)(22 << 20));    // 2 MB
  u16* QKb  = (u16*)(ws + (size_t)(24 << 20));    // 32 MB ([8192][2048] Q|K)
  u16* Vtr  = (u16*)(ws + (size_t)(56 << 20));    // 16 MB ([b][h][64][2048])

  cvt_f32_bf16<<<8192, 256, 0, stream>>>(x, xb, 8388608 / 4);
  cvt_weights<<<4096, 256, 0, stream>>>(Wq, Wk, Wv, Wo, Wqkv, Wob);

  // Q|K = xb @ Wqk^T ; Vtr = (xb @ Wv^T)^T  (transposed directly in epilogue)
  gemm_nt<1><<<dim3(16, 64), 256, 0, stream>>>(xb, Wqkv, QKb, 2048);
  gemm_nt<2><<<dim3(8, 64), 256, 0, stream>>>(xb, Wqkv + 2048 * 1024, Vtr, 0);

  rope_kernel<<<32768, 256, 0, stream>>>((u32*)QKb, tpos);

  attn_kernel<<<dim3(16, 64), 512, 0, stream>>>(QKb, Vtr, xb);

  // out = attn_out @ Wo^T  (fp32 epilogue)
  gemm_nt<0><<<dim3(8, 64), 256, 0, stream>>>(xb, Wob, out, 1024);
}

// Round 6
// 274.958 us; speedup vs baseline: 1.1156x; 1.1156x over previous
//
#include <hip/hip_runtime.h>
#include <cstdint>

using u16 = unsigned short;
using u32 = unsigned int;
using u64 = unsigned long long;

typedef __attribute__((ext_vector_type(8))) short short8v;   // 8 x bf16 (raw u16)
typedef __attribute__((ext_vector_type(4))) float f32x4;

#define MFMA_BF16(a, b, c) __builtin_amdgcn_mfma_f32_16x16x32_bf16((a), (b), (c), 0, 0, 0)

__device__ __forceinline__ u16 f2bf(float f) {
  u32 u = __float_as_uint(f);
  u += 0x7fffu + ((u >> 16) & 1u);   // RNE
  return (u16)(u >> 16);
}
__device__ __forceinline__ float bf2f(u32 s) { return __uint_as_float(s << 16); }
__device__ __forceinline__ u32 cvtpk(float a, float b) {
  u32 r;
  asm("v_cvt_pk_bf16_f32 %0, %1, %2" : "=v"(r) : "v"(a), "v"(b));
  return r;
}

__device__ __forceinline__ void g2l16(const u16* g, const u16* l) {
  __builtin_amdgcn_global_load_lds(
      (const __attribute__((address_space(1))) u32*)(uintptr_t)g,
      (__attribute__((address_space(3))) u32*)(u32)(uintptr_t)l, 16, 0, 0);
}

// ---------------- fp32 -> bf16 conversion ----------------
__global__ __launch_bounds__(256) void cvt_f32_bf16(const float* __restrict__ src,
                                                    u16* __restrict__ dst, int n4) {
  int i = blockIdx.x * blockDim.x + threadIdx.x;
  if (i >= n4) return;
  const float4 v = ((const float4*)src)[i];
  const u32 w0 = cvtpk(v.x, v.y), w1 = cvtpk(v.z, v.w);
  ((u64*)dst)[i] = (u64)w0 | ((u64)w1 << 32);
}

// all four 1024x1024 weights in one launch (grid 4096 x 256)
__global__ __launch_bounds__(256) void cvt_weights(const float* __restrict__ Wq,
                                                   const float* __restrict__ Wk,
                                                   const float* __restrict__ Wv,
                                                   const float* __restrict__ Wo,
                                                   u16* __restrict__ Wqkv,
                                                   u16* __restrict__ Wob) {
  const int i = blockIdx.x * 256 + threadIdx.x;   // 0 .. 4*262144-1
  const int sel = i >> 18, j = i & 0x3ffff;
  const float* src = (sel == 0) ? Wq : (sel == 1) ? Wk : (sel == 2) ? Wv : Wo;
  u16* dst = (sel == 0) ? Wqkv : (sel == 1) ? (Wqkv + 1048576)
           : (sel == 2) ? (Wqkv + 2097152) : Wob;
  const float4 v = ((const float4*)src)[j];
  const u32 w0 = cvtpk(v.x, v.y), w1 = cvtpk(v.z, v.w);
  ((u64*)dst)[j] = (u64)w0 | ((u64)w1 << 32);
}

// ---------------- NT GEMM: C[M][N] = A[M][K] * B[N][K]^T, bf16 in, K=1024 ----
// MODE: 0 = fp32 out, 1 = bf16 out, 2 = bf16 transposed-V out ([b*1024+col][2048])
// XCD-aware bijective swizzle (grid size must be a multiple of 8).
template <int MODE>
__global__ __launch_bounds__(256) void gemm_nt(const u16* __restrict__ A,
                                               const u16* __restrict__ B,
                                               void* __restrict__ C, int ldc) {
  constexpr int K = 1024;
  __shared__ u16 As[128 * 64];
  __shared__ u16 Bs[128 * 64];
  const int tid = threadIdx.x;
  const int lane = tid & 63, wave = tid >> 6;
  const int lr = lane & 15, lg = lane >> 4;
  const int nwg = gridDim.x * gridDim.y;
  int bid = blockIdx.y * gridDim.x + blockIdx.x;
  bid = (bid & 7) * (nwg >> 3) + (bid >> 3);
  const int bm = (bid / gridDim.x) * 128, bn = (bid % gridDim.x) * 128;
  const int wm = (wave >> 1) * 64, wn = (wave & 1) * 64;
  f32x4 acc[4][4] = {};
  for (int k0 = 0; k0 < K; k0 += 64) {
#pragma unroll
    for (int it = 0; it < 4; ++it) {
      const int ci = it * 4 + wave;
      const int li = ci * 512 + lane * 8;
      const int row = li >> 6, col = li & 63;
      g2l16(A + (size_t)(bm + row) * K + k0 + col, As + ci * 512);
      g2l16(B + (size_t)(bn + row) * K + k0 + col, Bs + ci * 512);
    }
    __syncthreads();
#pragma unroll
    for (int kk = 0; kk < 2; ++kk) {
      short8v af[4], bf[4];
#pragma unroll
      for (int m = 0; m < 4; ++m)
        af[m] = *(const short8v*)&As[(wm + m * 16 + lr) * 64 + kk * 32 + lg * 8];
#pragma unroll
      for (int n = 0; n < 4; ++n)
        bf[n] = *(const short8v*)&Bs[(wn + n * 16 + lr) * 64 + kk * 32 + lg * 8];
#pragma unroll
      for (int m = 0; m < 4; ++m)
#pragma unroll
        for (int n = 0; n < 4; ++n)
          acc[m][n] = MFMA_BF16(af[m], bf[n], acc[m][n]);
    }
    __syncthreads();
  }
#pragma unroll
  for (int m = 0; m < 4; ++m)
#pragma unroll
    for (int n = 0; n < 4; ++n) {
      if (MODE == 2) {
        const int col = bn + wn + n * 16 + lr;
        const int row0 = bm + wm + m * 16 + lg * 4;
        const int bb = row0 >> 11, sl = row0 & 2047;
        const u32 w0 = cvtpk(acc[m][n][0], acc[m][n][1]);
        const u32 w1 = cvtpk(acc[m][n][2], acc[m][n][3]);
        *(u64*)((u16*)C + ((size_t)(bb * 1024 + col)) * 2048 + sl) =
            (u64)w0 | ((u64)w1 << 32);
      } else {
#pragma unroll
        for (int r = 0; r < 4; ++r) {
          const int row = bm + wm + m * 16 + lg * 4 + r;
          const int col = bn + wn + n * 16 + lr;
          if (MODE == 1)
            ((u16*)C)[(size_t)row * ldc + col] = f2bf(acc[m][n][r]);
          else
            ((float*)C)[(size_t)row * ldc + col] = acc[m][n][r];
        }
      }
    }
}

// ---------------- RoPE in-place on QK buffer [8192][2048] -------------------
// Q half additionally scaled by 0.125*log2(e)  (attn softmax runs in exp2 domain)
__global__ __launch_bounds__(256) void rope_kernel(u32* __restrict__ QKu,
                                                   const int* __restrict__ tpos) {
  const int t = blockIdx.x * 256 + threadIdx.x;   // 0 .. 8192*1024-1
  const int row = t >> 10, pp = t & 1023;
  const u32 u = QKu[t];
  const float e = bf2f(u & 0xffffu), o = bf2f(u >> 16);
  const int i = pp & 31;                          // pair index within head (dk=64)
  const float pos = (float)tpos[row & 2047];
  const float ang = pos * __expf((float)i * -0.28782313662425574f);
  float sn, cs;
  sincosf(ang, &sn, &cs);
  const float sc = (pp < 512) ? 0.18033688011112042f : 1.0f;
  cs *= sc; sn *= sc;
  const float ne = e * cs - o * sn;
  const float no = o * cs + e * sn;
  QKu[t] = cvtpk(ne, no);
}

// ---------------- causal flash attention ------------------------------------
// grid (16, 64) x 512 threads (8 waves). Block = one 128-row q-tile of one
// (b,h); gx->qt map balances work over any 4-consecutive AND stride-8 sample.
// All 1024 blocks co-resident (4/CU by LDS). Swapped QK^T (mfma(K,Q)):
// lane owns q=lr, kv = c*16+lg*4+r; P stays in registers via cvt_pk; V B-frags
// use the matching slot->kv map. Defer-max (T13). Double-buffered K/V LDS,
// unrolled x2 (compile-time buffer index), 1 barrier per tile.
// NOTE: min-waves/EU left at 4 — (512,8) forces a 64-reg cap -> scratch spill
// (r5: VGPR 32, WRITE_SIZE 138 MB, 2x slower). Let LDS limit occupancy instead.
__global__ __launch_bounds__(512, 4) void attn_kernel(const u16* __restrict__ QK,
                                                      const u16* __restrict__ Vt,
                                                      u16* __restrict__ O) {
  const int gx = blockIdx.x;                       // 0..15
  const int qt = (gx < 8) ? ((gx & 1) ? gx : 15 - gx)
                          : ((gx & 1) ? 23 - gx : gx - 8);
  const int bh = blockIdx.y;
  const int h = bh & 15, b = bh >> 4;
  const int tid = threadIdx.x, lane = tid & 63, wave = tid >> 6;
  const int lr = lane & 15, lg = lane >> 4;
  __shared__ u16 Kt[2][64 * 72];
  __shared__ u16 Vs[2][64 * 72];
  const size_t bbase = (size_t)b * 2048;
  const int r_st = tid >> 3, cb_st = (tid & 7) * 8;   // staging: row, 8-u16 chunk
  const u16* Kbase = QK + (bbase + r_st) * 2048 + 1024 + h * 64 + cb_st;
  const u16* Vbase = Vt + ((size_t)(b * 16 + h) * 64 + r_st) * 2048 + cb_st;
  const int lds_off = r_st * 72 + cb_st;

  const int nkt = 2 * qt + 2;                      // always even
  const int qrow = qt * 128 + wave * 16;           // wave's first q-row
  short8v qf0, qf1;
  {
    const u16* qp = QK + (bbase + qrow + lr) * 2048 + h * 64 + lg * 8;
    qf0 = *(const short8v*)qp;
    qf1 = *(const short8v*)(qp + 32);
  }
  f32x4 oacc[4] = {};
  float m_run = -1e30f, l_run = 0.f;

  // prologue: stage tile 0 into buf0, prefetch tile 1 into regs
  short8v ka = *(const short8v*)Kbase;
  short8v va = *(const short8v*)Vbase;
  *(short8v*)&Kt[0][lds_off] = ka;
  *(short8v*)&Vs[0][lds_off] = va;
  ka = *(const short8v*)(Kbase + 64 * 2048);
  va = *(const short8v*)(Vbase + 64);

  auto compute = [&](const u16* Ktb, const u16* Vsb, const int kt) {
    if (kt * 64 > qrow + 15) return;   // wave fully masked for this tile
    f32x4 sacc[4] = {};
    __builtin_amdgcn_s_setprio(1);
#pragma unroll
    for (int c = 0; c < 4; ++c) {
      const short8v kf0 = *(const short8v*)&Ktb[(c * 16 + lr) * 72 + lg * 8];
      const short8v kf1 = *(const short8v*)&Ktb[(c * 16 + lr) * 72 + 32 + lg * 8];
      sacc[c] = MFMA_BF16(kf0, qf0, sacc[c]);
      sacc[c] = MFMA_BF16(kf1, qf1, sacc[c]);
    }
    __builtin_amdgcn_s_setprio(0);
    if (kt * 64 + 63 > qrow) {         // diagonal tile: causal mask
      const int qpos = qrow + lr;
#pragma unroll
      for (int c = 0; c < 4; ++c)
#pragma unroll
        for (int r = 0; r < 4; ++r)
          if (kt * 64 + c * 16 + lg * 4 + r > qpos) sacc[c][r] = -1e30f;
    }
    float mc[4];
#pragma unroll
    for (int c = 0; c < 4; ++c)
      mc[c] = fmaxf(fmaxf(sacc[c][0], sacc[c][1]), fmaxf(sacc[c][2], sacc[c][3]));
    float xm = fmaxf(fmaxf(mc[0], mc[1]), fmaxf(mc[2], mc[3]));
    xm = fmaxf(xm, __shfl_xor(xm, 16));
    xm = fmaxf(xm, __shfl_xor(xm, 32));
    if (!__all(xm <= m_run + 8.0f)) {  // defer-max: rescale only on real growth
      const float mn = fmaxf(m_run, xm);
      const float alpha = exp2f(m_run - mn);
      m_run = mn;
      l_run *= alpha;
#pragma unroll
      for (int r = 0; r < 4; ++r) {
        const float ao = __shfl(alpha, lg * 4 + r);
#pragma unroll
        for (int n = 0; n < 4; ++n) oacc[n][r] *= ao;
      }
    }
    float rc[4];
#pragma unroll
    for (int c = 0; c < 4; ++c) {
      f32x4 s = sacc[c];
#pragma unroll
      for (int r = 0; r < 4; ++r) s[r] = exp2f(s[r] - m_run);
      sacc[c] = s;
      rc[c] = (s[0] + s[1]) + (s[2] + s[3]);
    }
    float rs = (rc[0] + rc[1]) + (rc[2] + rc[3]);
    rs += __shfl_xor(rs, 16);
    rs += __shfl_xor(rs, 32);
    l_run += rs;
    short8v pa[2];
#pragma unroll
    for (int t = 0; t < 2; ++t) {
      union { short8v v; u32 w[4]; } P;
      P.w[0] = cvtpk(sacc[2 * t][0], sacc[2 * t][1]);
      P.w[1] = cvtpk(sacc[2 * t][2], sacc[2 * t][3]);
      P.w[2] = cvtpk(sacc[2 * t + 1][0], sacc[2 * t + 1][1]);
      P.w[3] = cvtpk(sacc[2 * t + 1][2], sacc[2 * t + 1][3]);
      pa[t] = P.v;
    }
    __builtin_amdgcn_s_setprio(1);
#pragma unroll
    for (int n = 0; n < 4; ++n) {
      const u16* vrow = &Vsb[(n * 16 + lr) * 72];
#pragma unroll
      for (int t = 0; t < 2; ++t) {
        union { short8v v; u64 d[2]; } V;
        V.d[0] = *(const u64*)(vrow + t * 32 + 4 * lg);
        V.d[1] = *(const u64*)(vrow + t * 32 + 16 + 4 * lg);
        oacc[n] = MFMA_BF16(pa[t], V.v, oacc[n]);
      }
    }
    __builtin_amdgcn_s_setprio(0);
  };

  for (int kt = 0; kt < nkt; kt += 2) {
    __syncthreads();                       // buf0 (tile kt) visible
    compute(Kt[0], Vs[0], kt);
    *(short8v*)&Kt[1][lds_off] = ka;       // stage tile kt+1
    *(short8v*)&Vs[1][lds_off] = va;
    const bool more = (kt + 2 < nkt);
    if (more) {                            // prefetch tile kt+2
      ka = *(const short8v*)(Kbase + (size_t)(kt + 2) * 64 * 2048);
      va = *(const short8v*)(Vbase + (kt + 2) * 64);
    }
    __syncthreads();                       // buf1 (tile kt+1) visible
    compute(Kt[1], Vs[1], kt + 1);
    if (more) {
      *(short8v*)&Kt[0][lds_off] = ka;     // stage tile kt+2
      *(short8v*)&Vs[0][lds_off] = va;
      ka = *(const short8v*)(Kbase + (size_t)(kt + 3) * 64 * 2048);
      va = *(const short8v*)(Vbase + (kt + 3) * 64);
    }
  }
  // ---- epilogue: O[q][d], q = qrow + lg*4 + r, d = n*16 + lr ----
#pragma unroll
  for (int r = 0; r < 4; ++r) {
    const float linv = 1.0f / __shfl(l_run, lg * 4 + r);
    const int qpos = qrow + lg * 4 + r;
#pragma unroll
    for (int n = 0; n < 4; ++n)
      O[(bbase + qpos) * 1024 + h * 64 + n * 16 + lr] = f2bf(oacc[n][r] * linv);
  }
}

// ---------------------------------------------------------------------------
extern "C" void kernel_launch(void* const* d_in, const int* in_sizes, int n_in,
                              void* d_out, int out_size, void* d_ws, size_t ws_size,
                              hipStream_t stream) {
  (void)in_sizes; (void)n_in; (void)out_size; (void)ws_size;
  const float* x   = (const float*)d_in[0];
  const int* tpos  = (const int*)d_in[1];
  const float* Wq  = (const float*)d_in[2];
  const float* Wk  = (const float*)d_in[3];
  const float* Wv  = (const float*)d_in[4];
  const float* Wo  = (const float*)d_in[5];
  float* out = (float*)d_out;

  // workspace layout (72 MB total)
  char* ws = (char*)d_ws;
  u16* xb   = (u16*)(ws);                         // 16 MB; reused as attn_out
  u16* Wqkv = (u16*)(ws + (size_t)(16 << 20));    // 6 MB  ([3072][1024])
  u16* Wob  = (u16*)(ws + (size_t)(22 << 20));    // 2 MB
  u16* QKb  = (u16*)(ws + (size_t)(24 << 20));    // 32 MB ([8192][2048] Q|K)
  u16* Vtr  = (u16*)(ws + (size_t)(56 << 20));    // 16 MB ([b][h][64][2048])

  cvt_f32_bf16<<<8192, 256, 0, stream>>>(x, xb, 8388608 / 4);
  cvt_weights<<<4096, 256, 0, stream>>>(Wq, Wk, Wv, Wo, Wqkv, Wob);

  // Q|K = xb @ Wqk^T ; Vtr = (xb @ Wv^T)^T  (transposed directly in epilogue)
  gemm_nt<1><<<dim3(16, 64), 256, 0, stream>>>(xb, Wqkv, QKb, 2048);
  gemm_nt<2><<<dim3(8, 64), 256, 0, stream>>>(xb, Wqkv + 2048 * 1024, Vtr, 0);

  rope_kernel<<<32768, 256, 0, stream>>>((u32*)QKb, tpos);

  attn_kernel<<<dim3(16, 64), 512, 0, stream>>>(QKb, Vtr, xb);

  // out = attn_out @ Wo^T  (fp32 epilogue)
  gemm_nt<0><<<dim3(8, 64), 256, 0, stream>>>(xb, Wob, out, 1024);
}

// Round 7
// 220.457 us; speedup vs baseline: 1.3913x; 1.2472x over previous
//
#include <hip/hip_runtime.h>
#include <cstdint>

using u16 = unsigned short;
using u32 = unsigned int;
using u64 = unsigned long long;

typedef __attribute__((ext_vector_type(8))) short short8v;   // 8 x bf16 (raw u16)
typedef __attribute__((ext_vector_type(4))) float f32x4;

#define MFMA_BF16(a, b, c) __builtin_amdgcn_mfma_f32_16x16x32_bf16((a), (b), (c), 0, 0, 0)

__device__ __forceinline__ u16 f2bf(float f) {
  u32 u = __float_as_uint(f);
  u += 0x7fffu + ((u >> 16) & 1u);   // RNE
  return (u16)(u >> 16);
}
__device__ __forceinline__ float bf2f(u32 s) { return __uint_as_float(s << 16); }
__device__ __forceinline__ u32 cvtpk(float a, float b) {
  u32 r;
  asm("v_cvt_pk_bf16_f32 %0, %1, %2" : "=v"(r) : "v"(a), "v"(b));
  return r;
}

__device__ __forceinline__ void g2l16(const u16* g, const u16* l) {
  __builtin_amdgcn_global_load_lds(
      (const __attribute__((address_space(1))) u32*)(uintptr_t)g,
      (__attribute__((address_space(3))) u32*)(u32)(uintptr_t)l, 16, 0, 0);
}

// ---------------- fp32 -> bf16 conversion ----------------
__global__ __launch_bounds__(256) void cvt_f32_bf16(const float* __restrict__ src,
                                                    u16* __restrict__ dst, int n4) {
  int i = blockIdx.x * blockDim.x + threadIdx.x;
  if (i >= n4) return;
  const float4 v = ((const float4*)src)[i];
  const u32 w0 = cvtpk(v.x, v.y), w1 = cvtpk(v.z, v.w);
  ((u64*)dst)[i] = (u64)w0 | ((u64)w1 << 32);
}

// all four 1024x1024 weights in one launch (grid 4096 x 256)
__global__ __launch_bounds__(256) void cvt_weights(const float* __restrict__ Wq,
                                                   const float* __restrict__ Wk,
                                                   const float* __restrict__ Wv,
                                                   const float* __restrict__ Wo,
                                                   u16* __restrict__ Wqkv,
                                                   u16* __restrict__ Wob) {
  const int i = blockIdx.x * 256 + threadIdx.x;   // 0 .. 4*262144-1
  const int sel = i >> 18, j = i & 0x3ffff;
  const float* src = (sel == 0) ? Wq : (sel == 1) ? Wk : (sel == 2) ? Wv : Wo;
  u16* dst = (sel == 0) ? Wqkv : (sel == 1) ? (Wqkv + 1048576)
           : (sel == 2) ? (Wqkv + 2097152) : Wob;
  const float4 v = ((const float4*)src)[j];
  const u32 w0 = cvtpk(v.x, v.y), w1 = cvtpk(v.z, v.w);
  ((u64*)dst)[j] = (u64)w0 | ((u64)w1 << 32);
}

// ---------------- NT GEMM: C[M][N] = A[M][K] * B[N][K]^T, bf16 in, K=1024 ----
// MODE: 0 = fp32 out, 1 = bf16 out, 2 = bf16 transposed-V out ([b*1024+col][2048])
// XCD-aware bijective swizzle (grid size must be a multiple of 8).
template <int MODE>
__global__ __launch_bounds__(256) void gemm_nt(const u16* __restrict__ A,
                                               const u16* __restrict__ B,
                                               void* __restrict__ C, int ldc) {
  constexpr int K = 1024;
  __shared__ u16 As[128 * 64];
  __shared__ u16 Bs[128 * 64];
  const int tid = threadIdx.x;
  const int lane = tid & 63, wave = tid >> 6;
  const int lr = lane & 15, lg = lane >> 4;
  const int nwg = gridDim.x * gridDim.y;
  int bid = blockIdx.y * gridDim.x + blockIdx.x;
  bid = (bid & 7) * (nwg >> 3) + (bid >> 3);
  const int bm = (bid / gridDim.x) * 128, bn = (bid % gridDim.x) * 128;
  const int wm = (wave >> 1) * 64, wn = (wave & 1) * 64;
  f32x4 acc[4][4] = {};
  for (int k0 = 0; k0 < K; k0 += 64) {
#pragma unroll
    for (int it = 0; it < 4; ++it) {
      const int ci = it * 4 + wave;
      const int li = ci * 512 + lane * 8;
      const int row = li >> 6, col = li & 63;
      g2l16(A + (size_t)(bm + row) * K + k0 + col, As + ci * 512);
      g2l16(B + (size_t)(bn + row) * K + k0 + col, Bs + ci * 512);
    }
    __syncthreads();
#pragma unroll
    for (int kk = 0; kk < 2; ++kk) {
      short8v af[4], bf[4];
#pragma unroll
      for (int m = 0; m < 4; ++m)
        af[m] = *(const short8v*)&As[(wm + m * 16 + lr) * 64 + kk * 32 + lg * 8];
#pragma unroll
      for (int n = 0; n < 4; ++n)
        bf[n] = *(const short8v*)&Bs[(wn + n * 16 + lr) * 64 + kk * 32 + lg * 8];
#pragma unroll
      for (int m = 0; m < 4; ++m)
#pragma unroll
        for (int n = 0; n < 4; ++n)
          acc[m][n] = MFMA_BF16(af[m], bf[n], acc[m][n]);
    }
    __syncthreads();
  }
#pragma unroll
  for (int m = 0; m < 4; ++m)
#pragma unroll
    for (int n = 0; n < 4; ++n) {
      if (MODE == 2) {
        const int col = bn + wn + n * 16 + lr;
        const int row0 = bm + wm + m * 16 + lg * 4;
        const int bb = row0 >> 11, sl = row0 & 2047;
        const u32 w0 = cvtpk(acc[m][n][0], acc[m][n][1]);
        const u32 w1 = cvtpk(acc[m][n][2], acc[m][n][3]);
        *(u64*)((u16*)C + ((size_t)(bb * 1024 + col)) * 2048 + sl) =
            (u64)w0 | ((u64)w1 << 32);
      } else {
#pragma unroll
        for (int r = 0; r < 4; ++r) {
          const int row = bm + wm + m * 16 + lg * 4 + r;
          const int col = bn + wn + n * 16 + lr;
          if (MODE == 1)
            ((u16*)C)[(size_t)row * ldc + col] = f2bf(acc[m][n][r]);
          else
            ((float*)C)[(size_t)row * ldc + col] = acc[m][n][r];
        }
      }
    }
}

// ---------------- RoPE in-place on QK buffer [8192][2048] -------------------
// Q half additionally scaled by 0.125*log2(e)  (attn softmax runs in exp2 domain)
__global__ __launch_bounds__(256) void rope_kernel(u32* __restrict__ QKu,
                                                   const int* __restrict__ tpos) {
  const int t = blockIdx.x * 256 + threadIdx.x;   // 0 .. 8192*1024-1
  const int row = t >> 10, pp = t & 1023;
  const u32 u = QKu[t];
  const float e = bf2f(u & 0xffffu), o = bf2f(u >> 16);
  const int i = pp & 31;                          // pair index within head (dk=64)
  const float pos = (float)tpos[row & 2047];
  const float ang = pos * __expf((float)i * -0.28782313662425574f);
  float sn, cs;
  sincosf(ang, &sn, &cs);
  const float sc = (pp < 512) ? 0.18033688011112042f : 1.0f;
  cs *= sc; sn *= sc;
  const float ne = e * cs - o * sn;
  const float no = o * cs + e * sn;
  QKu[t] = cvtpk(ne, no);
}

// ---------------- causal flash attention ------------------------------------
// 1024 blocks x 256 threads (4 waves). Block bid = p*64 + bh handles q-tiles
// {31-p, p} (64 rows each) of (b,h)=bh -> every block exactly 33 K-tile iters
// (perfect time balance), and all 16 blocks of one (b,h) are == mod 8 -> same
// XCD -> K/V L2-resident (r6 lesson: consecutive spread tripled FETCH_SIZE).
// 4 blocks/CU co-resident (LDS 36.8KB) = 4 independent barrier groups/CU.
// Swapped QK^T (mfma(K,Q)): lane owns q=lr, kv = c*16+lg*4+r; P stays in
// registers via cvt_pk; V B-frags use the matching slot->kv map. Defer-max.
// Double-buffered K/V LDS, 1 barrier per tile.
// NOTE: keep reg budget loose — (512,8)-style 64-reg caps cause scratch spill
// (r5: WRITE_SIZE 138 MB, 2x slower).
__global__ __launch_bounds__(256, 4) void attn_kernel(const u16* __restrict__ QK,
                                                      const u16* __restrict__ Vt,
                                                      u16* __restrict__ O) {
  const int bid = blockIdx.x;
  const int p = bid >> 6, bh = bid & 63;
  const int h = bh & 15, b = bh >> 4;
  const int tid = threadIdx.x, lane = tid & 63, wave = tid >> 6;
  const int lr = lane & 15, lg = lane >> 4;
  __shared__ u16 Kt[2][64 * 72];
  __shared__ u16 Vs[2][64 * 72];
  const size_t bbase = (size_t)b * 2048;
  const int r_st = tid >> 2, cb_st = (tid & 3) * 16;   // staging: row, 16-u16 chunk
  const u16* Kbase = QK + (bbase + r_st) * 2048 + 1024 + h * 64 + cb_st;
  const u16* Vbase = Vt + ((size_t)(b * 16 + h) * 64 + r_st) * 2048 + cb_st;
  const int lds_off = r_st * 72 + cb_st;

  const int qts[2] = {31 - p, p};
  for (int qi = 0; qi < 2; ++qi) {
    const int qt = qts[qi];
    const int nkt = qt + 1;
    const int qrow = qt * 64 + wave * 16;          // wave's first q-row
    short8v qf0, qf1;
    {
      const u16* qp = QK + (bbase + qrow + lr) * 2048 + h * 64 + lg * 8;
      qf0 = *(const short8v*)qp;
      qf1 = *(const short8v*)(qp + 32);
    }
    f32x4 oacc[4] = {};
    float m_run = -1e30f, l_run = 0.f;

    // prologue: stage tile 0 into buf0
    short8v ka0 = *(const short8v*)Kbase;
    short8v ka1 = *(const short8v*)(Kbase + 8);
    short8v va0 = *(const short8v*)Vbase;
    short8v va1 = *(const short8v*)(Vbase + 8);
    __syncthreads();   // previous q-tile's consumers done with LDS
    *(short8v*)&Kt[0][lds_off] = ka0;
    *(short8v*)&Kt[0][lds_off + 8] = ka1;
    *(short8v*)&Vs[0][lds_off] = va0;
    *(short8v*)&Vs[0][lds_off + 8] = va1;
    if (nkt > 1) {
      ka0 = *(const short8v*)(Kbase + 64 * 2048);
      ka1 = *(const short8v*)(Kbase + 64 * 2048 + 8);
      va0 = *(const short8v*)(Vbase + 64);
      va1 = *(const short8v*)(Vbase + 64 + 8);
    }
    int cur = 0;

    for (int kt = 0; kt < nkt; ++kt) {
      __syncthreads();                 // buf[cur] (tile kt) visible
      const u16* Ktb = Kt[cur];
      const u16* Vsb = Vs[cur];
      // ---- S^T = K Q^T : lane owns q = lr, kv = c*16 + lg*4 + r ----
      f32x4 sacc[4] = {};
      __builtin_amdgcn_s_setprio(1);
#pragma unroll
      for (int c = 0; c < 4; ++c) {
        const short8v kf0 = *(const short8v*)&Ktb[(c * 16 + lr) * 72 + lg * 8];
        const short8v kf1 = *(const short8v*)&Ktb[(c * 16 + lr) * 72 + 32 + lg * 8];
        sacc[c] = MFMA_BF16(kf0, qf0, sacc[c]);
        sacc[c] = MFMA_BF16(kf1, qf1, sacc[c]);
      }
      __builtin_amdgcn_s_setprio(0);
      if (kt == qt) {                  // diagonal tile: causal mask
        const int qpos = qrow + lr;
#pragma unroll
        for (int c = 0; c < 4; ++c)
#pragma unroll
          for (int r = 0; r < 4; ++r)
            if (kt * 64 + c * 16 + lg * 4 + r > qpos) sacc[c][r] = -1e30f;
      }
      float mc[4];
#pragma unroll
      for (int c = 0; c < 4; ++c)
        mc[c] = fmaxf(fmaxf(sacc[c][0], sacc[c][1]), fmaxf(sacc[c][2], sacc[c][3]));
      float xm = fmaxf(fmaxf(mc[0], mc[1]), fmaxf(mc[2], mc[3]));
      xm = fmaxf(xm, __shfl_xor(xm, 16));
      xm = fmaxf(xm, __shfl_xor(xm, 32));
      if (!__all(xm <= m_run + 8.0f)) {  // defer-max: rescale only on growth
        const float mn = fmaxf(m_run, xm);
        const float alpha = exp2f(m_run - mn);
        m_run = mn;
        l_run *= alpha;
#pragma unroll
        for (int r = 0; r < 4; ++r) {
          const float ao = __shfl(alpha, lg * 4 + r);
#pragma unroll
          for (int n = 0; n < 4; ++n) oacc[n][r] *= ao;
        }
      }
      float rc[4];
#pragma unroll
      for (int c = 0; c < 4; ++c) {
        f32x4 s = sacc[c];
#pragma unroll
        for (int r = 0; r < 4; ++r) s[r] = exp2f(s[r] - m_run);
        sacc[c] = s;
        rc[c] = (s[0] + s[1]) + (s[2] + s[3]);
      }
      float rs = (rc[0] + rc[1]) + (rc[2] + rc[3]);
      rs += __shfl_xor(rs, 16);
      rs += __shfl_xor(rs, 32);
      l_run += rs;
      // ---- pack P into A-frags (slot j<4: c=2t, j>=4: c=2t+1) ----
      short8v pa[2];
#pragma unroll
      for (int t = 0; t < 2; ++t) {
        union { short8v v; u32 w[4]; } P;
        P.w[0] = cvtpk(sacc[2 * t][0], sacc[2 * t][1]);
        P.w[1] = cvtpk(sacc[2 * t][2], sacc[2 * t][3]);
        P.w[2] = cvtpk(sacc[2 * t + 1][0], sacc[2 * t + 1][1]);
        P.w[3] = cvtpk(sacc[2 * t + 1][2], sacc[2 * t + 1][3]);
        pa[t] = P.v;
      }
      // ---- O += P V ; V slot j -> kv = 32t + 16*(j>>2) + 4lg + (j&3) ----
      __builtin_amdgcn_s_setprio(1);
#pragma unroll
      for (int n = 0; n < 4; ++n) {
        const u16* vrow = &Vsb[(n * 16 + lr) * 72];
#pragma unroll
        for (int t = 0; t < 2; ++t) {
          union { short8v v; u64 d[2]; } V;
          V.d[0] = *(const u64*)(vrow + t * 32 + 4 * lg);
          V.d[1] = *(const u64*)(vrow + t * 32 + 16 + 4 * lg);
          oacc[n] = MFMA_BF16(pa[t], V.v, oacc[n]);
        }
      }
      __builtin_amdgcn_s_setprio(0);
      // ---- stage tile kt+1 into other buffer; prefetch tile kt+2 ----
      if (kt + 1 < nkt) {
        const int nxt = cur ^ 1;
        *(short8v*)&Kt[nxt][lds_off] = ka0;
        *(short8v*)&Kt[nxt][lds_off + 8] = ka1;
        *(short8v*)&Vs[nxt][lds_off] = va0;
        *(short8v*)&Vs[nxt][lds_off + 8] = va1;
        if (kt + 2 < nkt) {
          const u16* kp = Kbase + (size_t)(kt + 2) * 64 * 2048;
          const u16* vp = Vbase + (kt + 2) * 64;
          ka0 = *(const short8v*)kp;
          ka1 = *(const short8v*)(kp + 8);
          va0 = *(const short8v*)vp;
          va1 = *(const short8v*)(vp + 8);
        }
        cur = nxt;
      }
    }
    // ---- epilogue: O[q][d], q = qrow + lg*4 + r, d = n*16 + lr ----
#pragma unroll
    for (int r = 0; r < 4; ++r) {
      const float linv = 1.0f / __shfl(l_run, lg * 4 + r);
      const int qpos = qrow + lg * 4 + r;
#pragma unroll
      for (int n = 0; n < 4; ++n)
        O[(bbase + qpos) * 1024 + h * 64 + n * 16 + lr] = f2bf(oacc[n][r] * linv);
    }
  }
}

// ---------------------------------------------------------------------------
extern "C" void kernel_launch(void* const* d_in, const int* in_sizes, int n_in,
                              void* d_out, int out_size, void* d_ws, size_t ws_size,
                              hipStream_t stream) {
  (void)in_sizes; (void)n_in; (void)out_size; (void)ws_size;
  const float* x   = (const float*)d_in[0];
  const int* tpos  = (const int*)d_in[1];
  const float* Wq  = (const float*)d_in[2];
  const float* Wk  = (const float*)d_in[3];
  const float* Wv  = (const float*)d_in[4];
  const float* Wo  = (const float*)d_in[5];
  float* out = (float*)d_out;

  // workspace layout (72 MB total)
  char* ws = (char*)d_ws;
  u16* xb   = (u16*)(ws);                         // 16 MB; reused as attn_out
  u16* Wqkv = (u16*)(ws + (size_t)(16 << 20));    // 6 MB  ([3072][1024])
  u16* Wob  = (u16*)(ws + (size_t)(22 << 20));    // 2 MB
  u16* QKb  = (u16*)(ws + (size_t)(24 << 20));    // 32 MB ([8192][2048] Q|K)
  u16* Vtr  = (u16*)(ws + (size_t)(56 << 20));    // 16 MB ([b][h][64][2048])

  cvt_f32_bf16<<<8192, 256, 0, stream>>>(x, xb, 8388608 / 4);
  cvt_weights<<<4096, 256, 0, stream>>>(Wq, Wk, Wv, Wo, Wqkv, Wob);

  // Q|K = xb @ Wqk^T ; Vtr = (xb @ Wv^T)^T  (transposed directly in epilogue)
  gemm_nt<1><<<dim3(16, 64), 256, 0, stream>>>(xb, Wqkv, QKb, 2048);
  gemm_nt<2><<<dim3(8, 64), 256, 0, stream>>>(xb, Wqkv + 2048 * 1024, Vtr, 0);

  rope_kernel<<<32768, 256, 0, stream>>>((u32*)QKb, tpos);

  attn_kernel<<<1024, 256, 0, stream>>>(QKb, Vtr, xb);

  // out = attn_out @ Wo^T  (fp32 epilogue)
  gemm_nt<0><<<dim3(8, 64), 256, 0, stream>>>(xb, Wob, out, 1024);
}